// Round 9
// baseline (146.501 us; speedup 1.0000x reference)
//
#include <hip/hip_runtime.h>

// CNN encoder as implicit-im2col GEMM:
//   A(M=32*2040, K=1024) x Wp(K=1024, N=256), Wp[fd][k] = filt[fd]*W_k[fd][k]
//   out = relu(A*Wp + b_k)
// Round 17: m97-mimetic residency fix. R8-R16 matrix: 16 waves/CU -> 48-55us,
// 8 waves/CU -> 60-64us, schedule within a rank = noise. Latency-bound; the
// only working lever is independent wave-group coverage. m97 (identical
// 2-barrier BK=32 loop, this chip) hits MfmaUtil 37% vs our 27% with ~3
// independent 4-wave blocks/CU (3 barrier groups) vs our 2x8 lockstep.
// This round: 128x128 block tile (N split in 2 halves), 256 thr / 4 waves
// of 64x64, sA full-K 36.7 KB + sB ring-2 BK=32 8 KB buffers = 52.7 KB
// -> 3 blocks/CU = 12 waves/CU in 3 independent barrier groups.
// Fragment-linear wp (0 bank conflicts), champion-exact 2-phase sync
// (stage(c+1) -> reads -> 8 MFMA -> __syncthreads).

#define L_SZ   2048
#define NWIN   2040   // L - F (reference uses L - F)
#define BM     128
#define MT     16

typedef __attribute__((ext_vector_type(8)))  short bf16x8;
typedef __attribute__((ext_vector_type(4)))  short bf16x4;
typedef __attribute__((ext_vector_type(16))) float f32x16;

static __device__ __forceinline__ short f2bf(float f) {
    union { float f; unsigned u; } v; v.f = f;
    unsigned r = v.u + 0x7FFFu + ((v.u >> 16) & 1u);
    return (short)(r >> 16);
}

static __device__ __forceinline__ void gload_lds16(const short* g, short* l) {
    __builtin_amdgcn_global_load_lds(
        (const __attribute__((address_space(1))) unsigned int*)g,
        (__attribute__((address_space(3))) unsigned int*)l, 16, 0, 0);
}

// ---- prep: wp6[c32][nh][slot][8 shorts]; c32 in [0,32) BK=32 chunks,
// nh in {0,1} 128-col halves, slot = c8*128 + n (512 slots of 16 B = 8 KB).
// Content: Wp[c32*32 + c8*8 + jj][nh*128 + n], jj=0..7, Wp[k][np] =
// Wk[k][np]*filt[k]. 32x32x16 bf16 B-fragment order for a 128-col panel:
// a wave's b-frag (ks,j) read is 32 contiguous slots -> conflict-free
// ds_read_b128; staging is lane-linear.
__global__ __launch_bounds__(256) void prep_w_kernel(
    const float* __restrict__ Wk, const float* __restrict__ filt,
    short* __restrict__ wp6)
{
    int g   = blockIdx.x * 256 + threadIdx.x;  // 32768 slots
    int c   = g >> 10;          // chunk 0..31
    int nh  = (g >> 9) & 1;     // col half
    int c8  = (g >> 7) & 3;     // 8-k subgroup
    int n   = g & 127;
    int np  = nh * 128 + n;
    int kb  = c * 32 + c8 * 8;
    bf16x8 o;
    #pragma unroll
    for (int jj = 0; jj < 8; ++jj)
        o[jj] = f2bf(Wk[(size_t)(kb + jj) * 256 + np] * filt[kb + jj]);
    *reinterpret_cast<bf16x8*>(&wp6[(size_t)g * 8]) = o;
}

__global__ __launch_bounds__(256, 3) void cnn_enc_kernel(
    const float* __restrict__ ub, const short* __restrict__ wp6,
    const float* __restrict__ bk, float* __restrict__ out)
{
    // A slab: 135 rows x 128 d bf16, stride 136 (a-frag b128 reads are
    // 2-way-per-bank = free). 36720 B.
    __shared__ short sA[135 * 136];
    // B: ring-2 of 8 KB (BK=32 x 128 cols), lane-linear fragment order.
    __shared__ short sB[2 * 4096];     // 16384 B (total 53104 -> 3 blk/CU)

    const int tid   = threadIdx.x;
    const int bid   = blockIdx.x;
    const int nh    = bid & 1;           // N-half 0..1
    const int mt    = (bid >> 1) & 15;   // M-tile 0..15
    const int batch = bid >> 5;          // 0..31
    const int l0    = mt * BM;

    const int lane = tid & 63;
    const int wave = tid >> 6;     // 0..3
    const int wm   = wave >> 1;    // 0..1  (64-row sub-tile)
    const int wn   = wave & 1;     // 0..1  (64-col sub-tile)
    const int l32  = lane & 31;
    const int half = lane >> 5;    // 0..1

    // ---- B chunk staging: 8 KB lane-linear, 2 gload_lds per thread.
    auto stageB = [&](int c, int buf) {
        const short* wpb = wp6 + ((size_t)c * 2 + nh) * 4096;
        #pragma unroll
        for (int r = 0; r < 2; ++r) {
            int ubase = r * 256 + wave * 64;        // 16B-unit, wave-uniform
            gload_lds16(wpb + (size_t)(ubase + lane) * 8,
                        &sB[buf * 4096 + ubase * 8]);
        }
    };

    // ---- prologue: A loads (oldest in FIFO), B chunk 0, convert+write A
    const float* ubb = ub + ((size_t)batch << 18);  // batch*2048*128
    float4 av[17];                                   // 4320 float4 / 256 thr
    #pragma unroll
    for (int u = 0; u < 17; ++u) {
        int idx = tid + u * 256;
        if (u < 16 || idx < 4320) {
            int r  = idx >> 5;             // row 0..134
            int c4 = idx & 31;             // float4 within row
            int rg = l0 + r; if (rg > L_SZ - 1) rg = L_SZ - 1;
            av[u] = *reinterpret_cast<const float4*>(
                ubb + ((size_t)rg << 7) + c4 * 4);
        }
    }
    stageB(0, 0);
    #pragma unroll
    for (int u = 0; u < 17; ++u) {
        int idx = tid + u * 256;
        if (u < 16 || idx < 4320) {
            int r  = idx >> 5;
            int c4 = idx & 31;
            bf16x4 o;
            o.x = f2bf(av[u].x); o.y = f2bf(av[u].y);
            o.z = f2bf(av[u].z); o.w = f2bf(av[u].w);
            *reinterpret_cast<bf16x4*>(&sA[r * 136 + c4 * 4]) = o;
        }
    }

    f32x16 acc[2][2];
    #pragma unroll
    for (int i = 0; i < 2; ++i)
        #pragma unroll
        for (int j = 0; j < 2; ++j)
            acc[i][j] = (f32x16){0.f,0.f,0.f,0.f,0.f,0.f,0.f,0.f,
                                 0.f,0.f,0.f,0.f,0.f,0.f,0.f,0.f};

    // a-frag base (shorts): row = wm*64 + i*32 + l32 (+f later), d = half*8
    int aoff[2];
    #pragma unroll
    for (int i = 0; i < 2; ++i)
        aoff[i] = (wm * 64 + i * 32 + l32) * 136 + half * 8;
    // b-frag base (shorts) in a buffer: slot = (ks*2+half)*128 + wn*64
    // + j*32 + l32 -> offset slot*8 (+ ks*2048 + j*256)
    const int boff = (half * 128 + wn * 64 + l32) * 8;

    __syncthreads();   // sA + sB buf0 visible (syncthreads drains vmcnt)

    // champion-exact 2-phase loop: stage(c+1) -> reads -> 8 MFMA -> barrier
    #pragma unroll 1
    for (int c = 0; c < 32; ++c) {
        if (c < 31) stageB(c + 1, (c + 1) & 1);
        const int f  = c >> 2, ds = c & 3;
        const int bb = (c & 1) * 4096;
        bf16x8 a[2][2], b[2][2];                    // [ks][i/j]
        #pragma unroll
        for (int ks = 0; ks < 2; ++ks) {
            #pragma unroll
            for (int i = 0; i < 2; ++i)
                a[ks][i] = *reinterpret_cast<const bf16x8*>(
                    &sA[aoff[i] + f * 136 + ds * 32 + ks * 16]);
            #pragma unroll
            for (int j = 0; j < 2; ++j)
                b[ks][j] = *reinterpret_cast<const bf16x8*>(
                    &sB[bb + boff + ks * 2048 + j * 256]);
        }
        #pragma unroll
        for (int ks = 0; ks < 2; ++ks)
            #pragma unroll
            for (int i = 0; i < 2; ++i)
                #pragma unroll
                for (int j = 0; j < 2; ++j)
                    acc[i][j] = __builtin_amdgcn_mfma_f32_32x32x16_bf16(
                        a[ks][i], b[ks][j], acc[i][j], 0, 0, 0);
        __syncthreads();   // frees buf(c), publishes buf(c+1)
    }

    // ---- epilogue: bias + relu
    // C/D 32x32: col = lane&31, row = (reg&3) + 8*(reg>>2) + 4*(lane>>5)
    #pragma unroll
    for (int j = 0; j < 2; ++j) {
        int n_glob = nh * 128 + wn * 64 + j * 32 + l32;
        float bias = bk[n_glob];
        #pragma unroll
        for (int i = 0; i < 2; ++i) {
            #pragma unroll
            for (int r = 0; r < 16; ++r) {
                int row = (r & 3) + 8 * (r >> 2) + 4 * half;
                int l = l0 + wm * 64 + i * 32 + row;
                if (l < NWIN) {
                    float v = acc[i][j][r] + bias;
                    out[((size_t)batch * NWIN + l) * 256 + n_glob] =
                        v > 0.f ? v : 0.f;
                }
            }
        }
    }
}

extern "C" void kernel_launch(void* const* d_in, const int* in_sizes, int n_in,
                              void* d_out, int out_size, void* d_ws, size_t ws_size,
                              hipStream_t stream) {
    const float* ub   = (const float*)d_in[0];  // (32,2048,128) fp32
    const float* filt = (const float*)d_in[1];  // (8,128) fp32
    const float* Wk   = (const float*)d_in[2];  // (1024,256) fp32
    const float* bk   = (const float*)d_in[3];  // (256,) fp32
    float* out = (float*)d_out;                 // (32,2040,256) fp32
    short* wp6 = (short*)d_ws;                  // 512 KB fragment-order Wp

    hipLaunchKernelGGL(prep_w_kernel, dim3(128), dim3(256), 0, stream,
                       Wk, filt, wp6);
    hipLaunchKernelGGL(cnn_enc_kernel, dim3(32 * MT * 2), dim3(256), 0, stream,
                       ub, wp6, bk, out);
}

// Round 10
// 131.036 us; speedup vs baseline: 1.1180x; 1.1180x over previous
//
#include <hip/hip_runtime.h>

// CNN encoder as implicit-im2col GEMM:
//   A(M=32*2040, K=1024) x Wp(K=1024, N=256), Wp[fd][k] = filt[fd]*W_k[fd][k]
//   out = relu(A*Wp + b_k)
// Round 18: max-occupancy quadrant (32 waves/CU). R8-R17 ladder is monotone
// in waves/CU (16 -> 48-55us, 8 -> 60-65, 7avg -> 84): latency-bound, and
// occupancy is the only lever that has ever moved the kernel. 32 waves/CU
// needs <=64 unified regs/wave: wave tile 32x64 (acc 2x f32x16 = 32 regs,
// frags 12, launch_bounds(512,8) enforces the 64-reg bin).
//   - BM=64, grid 32 batches x 32 mtiles = 1024 blocks = EXACTLY 4/CU
//     (R17's fatal 3-per-CU tail avoided by construction)
//   - sA 71x136 full-K im2col slab 19.3 KB; sB ring-2 of 8 KB (BK=16,
//     R14's fragment-linear layout, measured 0 bank conflicts)
//   - champion-exact 2-phase loop: stage(c+1) -> reads -> 2 MFMA -> sync
//   - 4 independent barrier groups/CU + 8 waves/SIMD cover latency

#define L_SZ   2048
#define NWIN   2040   // L - F (reference uses L - F)
#define BM     64
#define MT     32

typedef __attribute__((ext_vector_type(8)))  short bf16x8;
typedef __attribute__((ext_vector_type(4)))  short bf16x4;
typedef __attribute__((ext_vector_type(16))) float f32x16;

static __device__ __forceinline__ short f2bf(float f) {
    union { float f; unsigned u; } v; v.f = f;
    unsigned r = v.u + 0x7FFFu + ((v.u >> 16) & 1u);
    return (short)(r >> 16);
}

static __device__ __forceinline__ void gload_lds16(const short* g, short* l) {
    __builtin_amdgcn_global_load_lds(
        (const __attribute__((address_space(1))) unsigned int*)g,
        (__attribute__((address_space(3))) unsigned int*)l, 16, 0, 0);
}

// ---- prep: wp4[c16][slot][8 shorts], c16 in [0,64) BK=16 chunks of 8 KB,
// slot = half*256 + n (512 slots/chunk). Slot content: Wp[c16*16 + half*8
// + jj][n], jj=0..7, Wp[k][n] = Wk[k][n]*filt[k]. 32x32x16 bf16 B-fragment
// order: staging is lane-linear (slot = tid&511), a wave's b-frag read is
// 32 contiguous 16B slots per half-wave -> conflict-free ds_read_b128
// (measured 0 conflicts in R14/R15).
__global__ __launch_bounds__(256) void prep_w_kernel(
    const float* __restrict__ Wk, const float* __restrict__ filt,
    short* __restrict__ wp4)
{
    int g    = blockIdx.x * 256 + threadIdx.x;  // 32768 slots
    int c16  = g >> 9;          // chunk 0..63
    int s    = g & 511;
    int half = s >> 8;
    int n    = s & 255;
    int kb   = c16 * 16 + half * 8;
    bf16x8 o;
    #pragma unroll
    for (int jj = 0; jj < 8; ++jj)
        o[jj] = f2bf(Wk[(size_t)(kb + jj) * 256 + n] * filt[kb + jj]);
    *reinterpret_cast<bf16x8*>(&wp4[(size_t)g * 8]) = o;
}

__global__ __launch_bounds__(512, 8) void cnn_enc_kernel(
    const float* __restrict__ ub, const short* __restrict__ wp4,
    const float* __restrict__ bk, float* __restrict__ out)
{
    // A slab: 71 rows x 128 d bf16, stride 136. Full K=1024 im2col slab
    // for 64 output rows. 19312 B.
    __shared__ short sA[71 * 136];
    // B: ring-2 of 8 KB chunk buffers (BK=16), lane-linear staged.
    __shared__ short sB[2 * 4096];     // 16384 B (total 35696 -> 4 blk/CU)

    const int tid   = threadIdx.x;
    const int bid   = blockIdx.x;
    const int mt    = bid & 31;          // M-tile 0..31
    const int batch = bid >> 5;          // 0..31
    const int l0    = mt * BM;

    const int lane = tid & 63;
    const int wave = tid >> 6;     // 0..7
    const int wm   = wave >> 2;    // 0..1  (32-row sub-tile)
    const int wn   = wave & 3;     // 0..3  (64-col sub-tile)
    const int l32  = lane & 31;
    const int half = lane >> 5;    // 0..1

    // ---- B chunk staging: 8 KB lane-linear, ONE gload_lds per thread.
    auto stageB = [&](int c) {
        const short* src = wp4 + (size_t)c * 4096 + (size_t)tid * 8;
        gload_lds16(src, &sB[(c & 1) * 4096 + wave * 512]);
    };

    // ---- prologue: A loads (oldest in FIFO), B chunk 0, convert+write A
    {
        const float* ubb = ub + ((size_t)batch << 18);  // batch*2048*128
        float4 av[5];                                    // 71*32=2272 f4 / 512
        #pragma unroll
        for (int u = 0; u < 5; ++u) {
            int idx = tid + u * 512;
            if (u < 4 || idx < 2272) {
                int r  = idx >> 5;             // row 0..70
                int c4 = idx & 31;             // float4 within row
                int rg = l0 + r; if (rg > L_SZ - 1) rg = L_SZ - 1;
                av[u] = *reinterpret_cast<const float4*>(
                    ubb + ((size_t)rg << 7) + c4 * 4);
            }
        }
        stageB(0);
        #pragma unroll
        for (int u = 0; u < 5; ++u) {
            int idx = tid + u * 512;
            if (u < 4 || idx < 2272) {
                int r  = idx >> 5;
                int c4 = idx & 31;
                bf16x4 o;
                o.x = f2bf(av[u].x); o.y = f2bf(av[u].y);
                o.z = f2bf(av[u].z); o.w = f2bf(av[u].w);
                *reinterpret_cast<bf16x4*>(&sA[r * 136 + c4 * 4]) = o;
            }
        }
    }

    f32x16 acc0 = (f32x16){0.f,0.f,0.f,0.f,0.f,0.f,0.f,0.f,
                           0.f,0.f,0.f,0.f,0.f,0.f,0.f,0.f};
    f32x16 acc1 = acc0;

    // a-frag base (shorts): row = wm*32 + l32 (+f*136 later), d = half*8
    const int aoff = (wm * 32 + l32) * 136 + half * 8;
    // b-frag base (shorts) in a buffer: slot = half*256 + wn*64 (+j*32) + l32
    const int boff = (half * 256 + wn * 64 + l32) * 8;

    __syncthreads();   // sA + sB buf0 visible (syncthreads drains vmcnt)

    // champion-exact 2-phase loop over 64 BK=16 chunks:
    // stage(c+1) -> reads(c) -> 2 MFMA -> __syncthreads
    #pragma unroll 1
    for (int c = 0; c < 64; ++c) {
        if (c < 63) stageB(c + 1);
        const int f = c >> 3, dsub = c & 7;
        const int bb = (c & 1) * 4096;
        bf16x8 a = *reinterpret_cast<const bf16x8*>(
            &sA[aoff + f * 136 + dsub * 16]);
        bf16x8 b0 = *reinterpret_cast<const bf16x8*>(&sB[bb + boff]);
        bf16x8 b1 = *reinterpret_cast<const bf16x8*>(&sB[bb + boff + 256]);
        acc0 = __builtin_amdgcn_mfma_f32_32x32x16_bf16(a, b0, acc0, 0, 0, 0);
        acc1 = __builtin_amdgcn_mfma_f32_32x32x16_bf16(a, b1, acc1, 0, 0, 0);
        __syncthreads();   // frees buf(c), publishes buf(c+1)
    }

    // ---- epilogue: bias + relu, streaming stores
    // C/D 32x32: col = lane&31, row = (reg&3) + 8*(reg>>2) + 4*(lane>>5)
    #pragma unroll
    for (int j = 0; j < 2; ++j) {
        int n_glob = wn * 64 + j * 32 + l32;
        float bias = bk[n_glob];
        const f32x16& acc = j ? acc1 : acc0;
        #pragma unroll
        for (int r = 0; r < 16; ++r) {
            int row = (r & 3) + 8 * (r >> 2) + 4 * half;
            int l = l0 + wm * 32 + row;
            if (l < NWIN) {
                float v = acc[r] + bias;
                __builtin_nontemporal_store(
                    v > 0.f ? v : 0.f,
                    &out[((size_t)batch * NWIN + l) * 256 + n_glob]);
            }
        }
    }
}

extern "C" void kernel_launch(void* const* d_in, const int* in_sizes, int n_in,
                              void* d_out, int out_size, void* d_ws, size_t ws_size,
                              hipStream_t stream) {
    const float* ub   = (const float*)d_in[0];  // (32,2048,128) fp32
    const float* filt = (const float*)d_in[1];  // (8,128) fp32
    const float* Wk   = (const float*)d_in[2];  // (1024,256) fp32
    const float* bk   = (const float*)d_in[3];  // (256,) fp32
    float* out = (float*)d_out;                 // (32,2040,256) fp32
    short* wp4 = (short*)d_ws;                  // 512 KB BK=16 fragment-order Wp

    hipLaunchKernelGGL(prep_w_kernel, dim3(128), dim3(256), 0, stream,
                       Wk, filt, wp4);
    hipLaunchKernelGGL(cnn_enc_kernel, dim3(32 * MT), dim3(512), 0, stream,
                       ub, wp4, bk, out);
}

// Round 11
// 123.372 us; speedup vs baseline: 1.1875x; 1.0621x over previous
//
#include <hip/hip_runtime.h>

// CNN encoder as implicit-im2col GEMM:
//   A(M=32*2040, K=1024) x Wp(K=1024, N=256), Wp[fd][k] = filt[fd]*W_k[fd][k]
//   out = relu(A*Wp + b_k)
// Round 19: single-barrier-group mega-block. R8-R18 showed: per-SIMD
// resident MFMA work is register-file-capped (waves x acc <= 512 regs =>
// ~1033 cyc/CU-kstep in EVERY geometry), and the measured 3630-cyc period
// = 1033 MFMA + 2 x ~1300 per-BLOCK serial read/sync overhead -- the two
// co-resident blocks serialize phases on shared SIMDs. Fix: ONE 1024-thread
// block per CU (16 waves = 4/SIMD, same occupancy rank as champion):
//   - BM=256, grid 32x8 = 256 blocks = exactly 1/CU, no tail, no rounds
//   - sA full-K im2col slab 263x136 = 71.5 KB; sB ring-5 x 16 KB = 80 KB
//   - 2 chunks per barrier period (16 barriers vs champion's 32), counted
//     vmcnt(1) so staging is never drained in-loop (T4)
//   - single frag set (reads(2p)->MFMA->reads(2p+1)->MFMA) to stay <=128
//     regs -- hard requirement for a 1024-thr block at 4 waves/SIMD
//   - champion's wp2 XOR-swizzled fragment layout + epilogue verbatim

#define L_SZ   2048
#define NWIN   2040   // L - F (reference uses L - F)
#define BM     256
#define MT     8

typedef __attribute__((ext_vector_type(8)))  short bf16x8;
typedef __attribute__((ext_vector_type(4)))  short bf16x4;
typedef __attribute__((ext_vector_type(16))) float f32x16;

static __device__ __forceinline__ short f2bf(float f) {
    union { float f; unsigned u; } v; v.f = f;
    unsigned r = v.u + 0x7FFFu + ((v.u >> 16) & 1u);
    return (short)(r >> 16);
}

static __device__ __forceinline__ void gload_lds16(const short* g, short* l) {
    __builtin_amdgcn_global_load_lds(
        (const __attribute__((address_space(1))) unsigned int*)g,
        (__attribute__((address_space(3))) unsigned int*)l, 16, 0, 0);
}

// ---- prep: wp2 = 32 regions (BK=32 chunks) of 16KB, 1024 slots of 16B each.
// Slot w in region R: np = w>>2 (n 0..255), pos = w&3; holds
// Wp[np][R*32 + (pos^((np>>1)&3))*8 .. +8], Wp[k][n] = Wk[k][n]*filt[k].
// XOR swizzle baked in: staging lane-linear, b-frag ds_read_b128 balanced.
// (Champion R8 layout, verbatim.)
__global__ __launch_bounds__(256) void prep_w_kernel(
    const float* __restrict__ Wk, const float* __restrict__ filt,
    short* __restrict__ wp2)
{
    int g   = blockIdx.x * 256 + threadIdx.x;  // 32768 slots
    int R   = g >> 10;                         // chunk 0..31
    int w   = g & 1023;
    int np  = w >> 2;                          // n 0..255
    int pos = w & 3;
    int cs  = pos ^ ((np >> 1) & 3);
    int kb  = R * 32 + cs * 8;
    bf16x8 o;
    #pragma unroll
    for (int jj = 0; jj < 8; ++jj)
        o[jj] = f2bf(Wk[(size_t)(kb + jj) * 256 + np] * filt[kb + jj]);
    *reinterpret_cast<bf16x8*>(&wp2[(size_t)g * 8]) = o;
}

__global__ __launch_bounds__(1024, 4) void cnn_enc_kernel(
    const float* __restrict__ ub, const short* __restrict__ wp2,
    const float* __restrict__ bk, float* __restrict__ out)
{
    // A slab: 263 rows x 128 d bf16, stride 136 (a-frag b128 reads balanced)
    __shared__ short sA[263 * 136];    // 71,536 B
    // B: ring-5 of 16 KB BK=32 chunk buffers, lane-linear staged.
    __shared__ short sB[5 * 8192];     // 81,920 B  (total 153,456 -> 1 blk/CU)

    const int tid   = threadIdx.x;
    const int bid   = blockIdx.x;
    const int mt    = bid & 7;           // M-tile 0..7
    const int batch = bid >> 3;          // 0..31
    const int l0    = mt * BM;

    const int lane = tid & 63;
    const int wave = tid >> 6;     // 0..15
    const int wm   = wave >> 2;    // 0..3  (64-row sub-tile)
    const int wn   = wave & 3;     // 0..3  (64-col sub-tile)
    const int l32  = lane & 31;
    const int half = lane >> 5;    // 0..1

    // ---- B chunk staging: 16 KB lane-linear, ONE gload_lds per thread.
    auto stageB = [&](int c) {
        const short* src = wp2 + ((size_t)c * 1024 + tid) * 8;
        gload_lds16(src, &sB[(c % 5) * 8192 + wave * 512]);
    };

    // ---- prologue: A loads (oldest in FIFO), B chunks 0..2, convert A ----
    const float* ubb = ub + ((size_t)batch << 18);  // batch*2048*128
    {
        float4 av[9];                                // 263*32 = 8416 float4
        #pragma unroll
        for (int u = 0; u < 9; ++u) {
            int idx = tid + u * 1024;
            if (u < 8 || idx < 8416) {
                int r  = idx >> 5;             // row 0..262
                int c4 = idx & 31;             // float4 within row
                int rg = l0 + r; if (rg > L_SZ - 1) rg = L_SZ - 1;
                av[u] = *reinterpret_cast<const float4*>(
                    ubb + ((size_t)rg << 7) + c4 * 4);
            }
        }
        stageB(0); stageB(1); stageB(2);
        #pragma unroll
        for (int u = 0; u < 9; ++u) {
            int idx = tid + u * 1024;
            if (u < 8 || idx < 8416) {
                int r  = idx >> 5;
                int c4 = idx & 31;
                bf16x4 o;
                o.x = f2bf(av[u].x); o.y = f2bf(av[u].y);
                o.z = f2bf(av[u].z); o.w = f2bf(av[u].w);
                *reinterpret_cast<bf16x4*>(&sA[r * 136 + c4 * 4]) = o;
            }
        }
    }

    f32x16 acc[2][2];
    #pragma unroll
    for (int i = 0; i < 2; ++i)
        #pragma unroll
        for (int j = 0; j < 2; ++j)
            acc[i][j] = (f32x16){0.f,0.f,0.f,0.f,0.f,0.f,0.f,0.f,
                                 0.f,0.f,0.f,0.f,0.f,0.f,0.f,0.f};

    // a-frag base (shorts): row = wm*64 + i*32 + l32 (+f later),
    // d = ds*32 + ks*16 + half*8
    int aoff[2];
    #pragma unroll
    for (int i = 0; i < 2; ++i)
        aoff[i] = (wm * 64 + i * 32 + l32) * 136 + half * 8;
    // b-frag (champion verbatim): np = wn*64 + j*32 + l32;
    // addr = bb + np*32 + ((ks*2+half) ^ ((np>>1)&3))*8
    int bnp[2], bxor[2];
    #pragma unroll
    for (int j = 0; j < 2; ++j) {
        int np = wn * 64 + j * 32 + l32;
        bnp[j]  = np * 32;
        bxor[j] = (np >> 1) & 3;
    }

    // one chunk's fragment consumption (single frag set: <=128 reg budget)
    auto doChunk = [&](int c) {
        const int f  = c >> 2, ds = c & 3;
        const int bb = (c % 5) * 8192;
        bf16x8 a[2][2], b[2][2];                    // [ks][i/j]
        #pragma unroll
        for (int ks = 0; ks < 2; ++ks) {
            #pragma unroll
            for (int i = 0; i < 2; ++i)
                a[ks][i] = *reinterpret_cast<const bf16x8*>(
                    &sA[aoff[i] + f * 136 + ds * 32 + ks * 16]);
            #pragma unroll
            for (int j = 0; j < 2; ++j) {
                int c8 = ks * 2 + half;
                b[ks][j] = *reinterpret_cast<const bf16x8*>(
                    &sB[bb + bnp[j] + (c8 ^ bxor[j]) * 8]);
            }
        }
        __builtin_amdgcn_s_setprio(1);
        #pragma unroll
        for (int ks = 0; ks < 2; ++ks)
            #pragma unroll
            for (int i = 0; i < 2; ++i)
                #pragma unroll
                for (int j = 0; j < 2; ++j)
                    acc[i][j] = __builtin_amdgcn_mfma_f32_32x32x16_bf16(
                        a[ks][i], b[ks][j], acc[i][j], 0, 0, 0);
        __builtin_amdgcn_s_setprio(0);
    };

    // A writes visible; chunks 0,1 landed (chunk 2 still in flight).
    asm volatile("s_waitcnt vmcnt(1) lgkmcnt(0)" ::: "memory");
    __builtin_amdgcn_s_barrier();
    __builtin_amdgcn_sched_barrier(0);

    // period p (p=0..15): chunks {2p, 2p+1} from ring; stage {2p+3, 2p+4};
    // barrier with vmcnt(1) -> chunk 2p+3 landed, 2p+4 may stay in flight.
    // Ring-5 invariant: live bufs at period p = {2p..2p+4} % 5, all distinct.
    #pragma unroll 1
    for (int p = 0; p < 16; ++p) {
        const int c0 = 2 * p;
        if (c0 + 3 < 32) stageB(c0 + 3);
        if (c0 + 4 < 32) stageB(c0 + 4);
        doChunk(c0);
        doChunk(c0 + 1);
        if (p < 15) {
            if (p < 14) { asm volatile("s_waitcnt vmcnt(1)" ::: "memory"); }
            else        { asm volatile("s_waitcnt vmcnt(0)" ::: "memory"); }
            __builtin_amdgcn_s_barrier();
            __builtin_amdgcn_sched_barrier(0);
        }
    }

    // ---- epilogue: bias + relu, streaming stores
    // C/D 32x32: col = lane&31, row = (reg&3) + 8*(reg>>2) + 4*(lane>>5)
    #pragma unroll
    for (int j = 0; j < 2; ++j) {
        int n_glob = wn * 64 + j * 32 + l32;
        float bias = bk[n_glob];
        #pragma unroll
        for (int i = 0; i < 2; ++i) {
            #pragma unroll
            for (int r = 0; r < 16; ++r) {
                int row = (r & 3) + 8 * (r >> 2) + 4 * half;
                int l = l0 + wm * 64 + i * 32 + row;
                if (l < NWIN) {
                    float v = acc[i][j][r] + bias;
                    __builtin_nontemporal_store(
                        v > 0.f ? v : 0.f,
                        &out[((size_t)batch * NWIN + l) * 256 + n_glob]);
                }
            }
        }
    }
}

extern "C" void kernel_launch(void* const* d_in, const int* in_sizes, int n_in,
                              void* d_out, int out_size, void* d_ws, size_t ws_size,
                              hipStream_t stream) {
    const float* ub   = (const float*)d_in[0];  // (32,2048,128) fp32
    const float* filt = (const float*)d_in[1];  // (8,128) fp32
    const float* Wk   = (const float*)d_in[2];  // (1024,256) fp32
    const float* bk   = (const float*)d_in[3];  // (256,) fp32
    float* out = (float*)d_out;                 // (32,2040,256) fp32
    short* wp2 = (short*)d_ws;                  // 512 KB re-tiled Wp^T

    hipLaunchKernelGGL(prep_w_kernel, dim3(128), dim3(256), 0, stream,
                       Wk, filt, wp2);
    hipLaunchKernelGGL(cnn_enc_kernel, dim3(32 * MT), dim3(1024), 0, stream,
                       ub, wp2, bk, out);
}